// Round 2
// baseline (140.418 us; speedup 1.0000x reference)
//
#include <hip/hip_runtime.h>

// Sin/cos position embedding: out[b, 2i] = sin(t[b] * N^(-2i/D)),
//                             out[b, 2i+1] = cos(t[b] * N^(-2i/D))
// Write-BW bound: 128 MiB out, 64 KiB in. One thread per float4 (two pairs).

__global__ __launch_bounds__(256) void sinpos_kernel(
    const float* __restrict__ t,
    float4* __restrict__ out,
    int q,        // D/4 = float4s per row
    float c)      // -2*log2(N_BASE)/D, so inv_freq = exp2(c*i)
{
    int j = blockIdx.x * blockDim.x + threadIdx.x;
    int b = blockIdx.y;              // wave-uniform -> t[b] is a scalar load
    if (j >= q) return;

    float tv = t[b];
    float i0 = (float)(2 * j);
    float i1 = i0 + 1.0f;

    // inv_freq via native exp2 (v_exp_f32)
    float f0 = __builtin_amdgcn_exp2f(c * i0);
    float f1 = __builtin_amdgcn_exp2f(c * i1);
    float a0 = tv * f0;
    float a1 = tv * f1;

    // v_sin_f32 / v_cos_f32 take REVOLUTIONS; reduce explicitly.
    const float inv2pi = 0.15915494309189535f;
    float r0 = a0 * inv2pi; r0 -= __builtin_floorf(r0);
    float r1 = a1 * inv2pi; r1 -= __builtin_floorf(r1);

    float4 v;
    v.x = __builtin_amdgcn_sinf(r0);
    v.y = __builtin_amdgcn_cosf(r0);
    v.z = __builtin_amdgcn_sinf(r1);
    v.w = __builtin_amdgcn_cosf(r1);

    out[(size_t)b * q + j] = v;
}

extern "C" void kernel_launch(void* const* d_in, const int* in_sizes, int n_in,
                              void* d_out, int out_size, void* d_ws, size_t ws_size,
                              hipStream_t stream) {
    const float* t = (const float*)d_in[0];
    float* out = (float*)d_out;

    int B = in_sizes[0];             // 16384
    int D = out_size / B;            // 2048
    int q = D / 4;                   // float4s per row

    // c = -2*log2(10000)/D ; log2(10000) = 13.287712379549449
    float c = (float)(-2.0 * 13.287712379549449 / (double)D);

    dim3 block(256);
    dim3 grid((q + 255) / 256, B);
    sinpos_kernel<<<grid, block, 0, stream>>>(t, (float4*)out, q, c);
}

// Round 3
// 134.978 us; speedup vs baseline: 1.0403x; 1.0403x over previous
//
#include <hip/hip_runtime.h>

// Sin/cos position embedding: out[b, 2i] = sin(t[b] * N^(-2i/D)),
//                             out[b, 2i+1] = cos(t[b] * N^(-2i/D))
// 128 MiB written, 64 KiB read -> pure write-BW problem.
//
// Structure: persistent-ish blocks. Each thread owns ONE float4 column
// (frequency pair), computes exp2 once, then streams 16 B stores down
// `rows_per_block` rows. t[b] is wave-uniform -> scalar loads.

__global__ __launch_bounds__(256) void sinpos_kernel(
    const float* __restrict__ t,
    float4* __restrict__ out,
    int q,                // D/4 = float4s per row
    int rows_per_block,
    float c)              // -2*log2(N_BASE)/D, so inv_freq = exp2(c*i)
{
    int j = blockIdx.x * blockDim.x + threadIdx.x;   // float4 column
    if (j >= q) return;
    int b0 = blockIdx.y * rows_per_block;

    // Per-thread frequency pair: computed ONCE, reused for all rows.
    float i0 = (float)(2 * j);
    float f0 = __builtin_amdgcn_exp2f(c * i0);
    float f1 = __builtin_amdgcn_exp2f(c * (i0 + 1.0f));

    const float inv2pi = 0.15915494309189535f;   // fold /2pi into t
    float4* p = out + (size_t)b0 * q + j;

#pragma unroll 4
    for (int r = 0; r < rows_per_block; ++r) {
        float ts = t[b0 + r] * inv2pi;           // wave-uniform
        float r0 = ts * f0; r0 -= __builtin_floorf(r0);
        float r1 = ts * f1; r1 -= __builtin_floorf(r1);
        float4 v;
        v.x = __builtin_amdgcn_sinf(r0);
        v.y = __builtin_amdgcn_cosf(r0);
        v.z = __builtin_amdgcn_sinf(r1);
        v.w = __builtin_amdgcn_cosf(r1);
        *p = v;
        p += q;
    }
}

extern "C" void kernel_launch(void* const* d_in, const int* in_sizes, int n_in,
                              void* d_out, int out_size, void* d_ws, size_t ws_size,
                              hipStream_t stream) {
    const float* t = (const float*)d_in[0];
    float* out = (float*)d_out;

    int B = in_sizes[0];             // 16384
    int D = out_size / B;            // 2048
    int q = D / 4;                   // 512 float4s per row

    // c = -2*log2(10000)/D ; log2(10000) = 13.287712379549449
    float c = (float)(-2.0 * 13.287712379549449 / (double)D);

    // ~2 blocks/CU: grid = (q/256) x (B/rows_per_block)
    int rows_per_block = 64;
    while (rows_per_block > 1 && (B % rows_per_block) != 0) rows_per_block >>= 1;

    dim3 block(256);
    dim3 grid((q + 255) / 256, B / rows_per_block);
    sinpos_kernel<<<grid, block, 0, stream>>>(t, (float4*)out, q, rows_per_block, c);
}

// Round 4
// 134.971 us; speedup vs baseline: 1.0404x; 1.0001x over previous
//
#include <hip/hip_runtime.h>

// Sin/cos position embedding: out[b, 2i] = sin(t[b] * N^(-2i/D)),
//                             out[b, 2i+1] = cos(t[b] * N^(-2i/D))
// 128 MiB written, 64 KiB read -> pure write-BW problem.
//
// Structure: each thread owns ONE float4 column (frequency pair, exp2 once),
// streams RPB rows of 16 B stores. t-values for the row tile are prefetched
// into a uniform array up front (b0 is 64B-aligned, loads wave-uniform with
// const offsets -> compiler merges into s_load_dwordx16), so the row loop
// has no memory dependency. RPB=16 -> 2048 blocks -> 32 waves/CU (full occ).

#define RPB 16

__global__ __launch_bounds__(256) void sinpos_kernel(
    const float* __restrict__ t,
    float4* __restrict__ out,
    int q,                // D/4 = float4s per row
    float c)              // -2*log2(N_BASE)/D, so inv_freq = exp2(c*i)
{
    int j = blockIdx.x * blockDim.x + threadIdx.x;   // float4 column
    if (j >= q) return;
    int b0 = blockIdx.y * RPB;

    // Per-thread frequency pair: computed ONCE, reused for all rows.
    float i0 = (float)(2 * j);
    float f0 = __builtin_amdgcn_exp2f(c * i0);
    float f1 = __builtin_amdgcn_exp2f(c * (i0 + 1.0f));

    // Prefetch the tile's t values (wave-uniform, const offsets -> SMEM batch).
    const float inv2pi = 0.15915494309189535f;   // fold 1/2pi into t
    float ts[RPB];
#pragma unroll
    for (int r = 0; r < RPB; ++r) ts[r] = t[b0 + r] * inv2pi;

    float4* p = out + (size_t)b0 * q + j;
#pragma unroll
    for (int r = 0; r < RPB; ++r) {
        float r0 = ts[r] * f0; r0 -= __builtin_floorf(r0);
        float r1 = ts[r] * f1; r1 -= __builtin_floorf(r1);
        float4 v;
        v.x = __builtin_amdgcn_sinf(r0);
        v.y = __builtin_amdgcn_cosf(r0);
        v.z = __builtin_amdgcn_sinf(r1);
        v.w = __builtin_amdgcn_cosf(r1);
        *p = v;
        p += q;
    }
}

extern "C" void kernel_launch(void* const* d_in, const int* in_sizes, int n_in,
                              void* d_out, int out_size, void* d_ws, size_t ws_size,
                              hipStream_t stream) {
    const float* t = (const float*)d_in[0];
    float* out = (float*)d_out;

    int B = in_sizes[0];             // 16384
    int D = out_size / B;            // 2048
    int q = D / 4;                   // 512 float4s per row

    // c = -2*log2(10000)/D ; log2(10000) = 13.287712379549449
    float c = (float)(-2.0 * 13.287712379549449 / (double)D);

    dim3 block(256);
    dim3 grid((q + 255) / 256, B / RPB);   // B=16384 divisible by 16
    sinpos_kernel<<<grid, block, 0, stream>>>(t, (float4*)out, q, c);
}